// Round 23
// baseline (120.340 us; speedup 1.0000x reference)
//
#include <hip/hip_runtime.h>

// Depthwise 7x7 true-convolution (flipped kernel, SAME zero pad) + mish,
// via MFMA (v_mfma_f32_16x16x32_f16) with banded-Toeplitz weight matrices.
// Round-23: BARRIER-FREE main loop via column-partitioned wave-private rings.
// R13..R22 established: traffic near-ideal, no pipe >50%, dur = HBM floor
// (78us) + VALU issue (~35us) ADDED, i.e. phases serialize because the
// per-tile s_barrier locks all 4 waves into the same phase (no loads issued
// during a block's compute phase; ~3-4 resident blocks can't cover).
// Fix: wave = private 64-col strip x 128-row band with its OWN 40-row ring
// (40 x 80 halfs = 6.4 KB; 4 waves = 25.6 KB). The 8-col halos overlap the
// neighbor strip's data -> L2-resident -> HBM fetch unchanged (unlike R14's
// vertical-halo penalty). NO cross-wave LDS deps -> zero main-loop barriers;
// wave-local s_waitcnt lgkmcnt(0) orders own ds_write -> next ds_read.
// Ring disjointness per wave: reads [W-3,W+18] vs writes [W+19,W+34],
// diff 1..37 mod 40 -> disjoint. T14 split kept (raw loads early, cvt+write
// late). waves_per_eu(2,7): allocator-free regime (R19/R20 lesson: min>=4
// pins the 64-VGPR tier and spills).
//
// Ring layout (per wave): slot s = gr mod 40, ring cols 0..79 = global cols
// c0-8 .. c0+71 (f16). OOB cols/rows staged as zeros = SAME padding.
// A_p[i,k] = ring[(W+i+p-3)%40][16*t4 + k]  (global col c0+16t4-8+k)
// B_p[k,j] = W'[p][k-j-5] (banded), W'[p][q] = kern[6-p][6-q].
// MFMA C layout (m89): col = lane&15, row = (lane>>4)*4 + reg.
// A-read banks: word = 40*slot + 8*t4 + 4*lk; start = 4*(2*(lrow&3)+lk)+c
// -> all 8 even-word residues x 8 lanes x 4 words = uniform 8 words/bank.

#define HW 256
#define RING 40
#define WPITCH 80          // halfs per ring row (160 B)
#define TPB 8              // tiles per block (half a plane)

typedef _Float16 f16x8 __attribute__((ext_vector_type(8)));
typedef float    f32x4 __attribute__((ext_vector_type(4)));
typedef __fp16   h2    __attribute__((ext_vector_type(2)));
union U32H2 { unsigned u; h2 h; };
union BFU   { uint4 u; f16x8 h; };

__device__ __forceinline__ float mish_f(float y) {
    float t = __expf(y);            // inf-safe: d -> inf -> 2/d -> 0 -> y*1
    float u = 1.0f + t;
    float d = __fmaf_rn(u, u, 1.0f);
    return y * (1.0f - __fdividef(2.0f, d));
}

__global__ __launch_bounds__(256)
__attribute__((amdgpu_waves_per_eu(2, 7)))
void dwconv7_mish_wring(const float* __restrict__ x,
                        const float* __restrict__ kern,
                        float* __restrict__ out) {
    // 4 wave-private rings, 6400 B each = 25,600 B. B (7168 B) aliases
    // rings[0..1] during init only.
    __shared__ __align__(16) _Float16 rings[4][RING * WPITCH];

    const int tid  = threadIdx.x;
    const int lane = tid & 63;
    const int w    = tid >> 6;           // wave -> 64-col strip
    const int lrow = lane & 15;
    const int lk   = lane >> 4;
    const int c0   = w << 6;

    const int bid   = blockIdx.x;
    const int plane = bid >> 1;
    const int r0    = (bid & 1) << 7;    // 0 or 128

    const float* __restrict__ xp = x + (size_t)plane * (HW * HW);
    float* __restrict__ op = out + (size_t)plane * (HW * HW);

    unsigned* lds_B = (unsigned*)&rings[0][0];   // init-time alias (12.8 KB avail)

    // Flipped kernel in SGPRs: kf[p*7+q] = kern[6-p][6-q]
    float kf[49];
    #pragma unroll
    for (int i = 0; i < 49; ++i) {
        int p = i / 7, q = i - p * 7;
        kf[i] = __int_as_float(__builtin_amdgcn_readfirstlane(
                    __float_as_int(kern[(6 - p) * 7 + (6 - q)])));
    }

    // Banded-Toeplitz B_p[16][32] f16, word idx = p*256 + j*16 + k/2.
    {
        const int j  = tid >> 4;
        const int kw = tid & 15;
        #pragma unroll
        for (int p = 0; p < 7; ++p) {
            const int d0 = 2 * kw - j - 5;
            const int d1 = d0 + 1;
            float v0 = 0.f, v1 = 0.f;
            #pragma unroll
            for (int q = 0; q < 7; ++q) {
                v0 = (d0 == q) ? kf[p * 7 + q] : v0;
                v1 = (d1 == q) ? kf[p * 7 + q] : v1;
            }
            U32H2 u; u.h = __builtin_amdgcn_cvt_pkrtz(v0, v1);
            lds_B[p * 256 + tid] = u.u;
        }
    }
    __syncthreads();

    // B fragments hoisted: B[k=8lk+e, j=lrow], contiguous 16 B per lane.
    f16x8 bfrag[7];
    #pragma unroll
    for (int p = 0; p < 7; ++p) {
        BFU bu;
        bu.u = ((const uint4*)lds_B)[(p << 6) + (lrow << 2) + lk];
        bfrag[p] = bu.h;
    }
    __syncthreads();   // bfrag reads done before rings overwrite the B alias

    _Float16* ring = rings[w];

    // Per-lane staging decomposition: granule idx = lane + 64*i covers
    // (row r = idx/20, col-granule g = idx%20); granule = float4 = 4 cols,
    // global col gc = c0 - 8 + 4g; clamped address + zero mask for OOB.
    int ro_[7]; int gcc_[7]; unsigned cm_[7];
    #pragma unroll
    for (int i = 0; i < 7; ++i) {
        int idx = lane + (i << 6);
        int r = idx / 20, g = idx - 20 * r;
        ro_[i] = r;
        int gc = c0 - 8 + 4 * g;
        cm_[i]  = ((unsigned)gc <= (unsigned)(HW - 4)) ? 0xffffffffu : 0u;
        gcc_[i] = gc < 0 ? 0 : (gc > HW - 4 ? HW - 4 : gc);
    }

    // Prologue: stage rows gr = r0-3 .. r0+18 into own ring (22 rows x 20
    // granules = 440; i=6 only lanes < 56). Direct masked cvt+write.
    #pragma unroll
    for (int i = 0; i < 7; ++i) {
        if (i < 6 || lane < 56) {
            const int gr  = r0 - 3 + ro_[i];
            const int grc = gr < 0 ? 0 : (gr > HW - 1 ? HW - 1 : gr);
            float4 f = *(const float4*)(xp + (grc << 8) + gcc_[i]);
            const unsigned m = ((unsigned)gr < (unsigned)HW) ? cm_[i] : 0u;
            U32H2 a, b;
            a.h = __builtin_amdgcn_cvt_pkrtz(
                      __uint_as_float(__float_as_uint(f.x) & m),
                      __uint_as_float(__float_as_uint(f.y) & m));
            b.h = __builtin_amdgcn_cvt_pkrtz(
                      __uint_as_float(__float_as_uint(f.z) & m),
                      __uint_as_float(__float_as_uint(f.w) & m));
            const int slot = (gr + RING) % RING;
            ((uint2*)ring)[slot * 20 + (lane + (i << 6)) - 20 * ro_[i]] =
                make_uint2(a.u, b.u);
        }
    }

    // Main staging slots (i<5, 320 granules exactly): sm = (r0+19+r) % 40,
    // advanced +16 mod 40 per tile.
    int sm_[5];
    #pragma unroll
    for (int i = 0; i < 5; ++i) sm_[i] = (r0 + 19 + ro_[i]) % RING;
    int go_[5];
    #pragma unroll
    for (int i = 0; i < 5; ++i) go_[i] = (lane + (i << 6)) - 20 * ro_[i];

    int b0 = (r0 + 37) % RING;           // slot of gr = W-3 at t=0

    float4 rf[5];

    #pragma unroll 1
    for (int t = 0; t < TPB; ++t) {
        const int W = r0 + (t << 4);

        // ---- step 1: issue next tile's RAW loads (rows W+19..W+34) ----
        if (t + 1 < TPB) {
            #pragma unroll
            for (int i = 0; i < 5; ++i) {
                const int gr  = W + 19 + ro_[i];
                const int grc = gr > HW - 1 ? HW - 1 : gr;   // gr >= 19
                rf[i] = *(const float4*)(xp + (grc << 8) + gcc_[i]);
            }
        }
        __builtin_amdgcn_sched_barrier(0);

        // wave-local: own prior ds_writes visible to our ds_reads
        asm volatile("s_waitcnt lgkmcnt(0)" ::: "memory");
        __builtin_amdgcn_sched_barrier(0);

        // ---- step 2: compute tile (16 rows x 64 cols) from own ring ----
        int sa[7];
        #pragma unroll
        for (int p = 0; p < 7; ++p) {
            int s = b0 + lrow + p;
            s -= (s >= RING) ? RING : 0;
            sa[p] = s * WPITCH;
        }
        #pragma unroll
        for (int t4 = 0; t4 < 4; ++t4) {
            f32x4 acc = {0.f, 0.f, 0.f, 0.f};
            #pragma unroll
            for (int p = 0; p < 7; ++p) {
                f16x8 a = *(const f16x8*)(ring + sa[p] + 16 * t4 + 8 * lk);
                acc = __builtin_amdgcn_mfma_f32_16x16x32_f16(a, bfrag[p], acc,
                                                             0, 0, 0);
            }
            const int col = c0 + 16 * t4 + lrow;
            const int rb  = W + (lk << 2);
            op[(rb + 0) * HW + col] = mish_f(acc[0]);
            op[(rb + 1) * HW + col] = mish_f(acc[1]);
            op[(rb + 2) * HW + col] = mish_f(acc[2]);
            op[(rb + 3) * HW + col] = mish_f(acc[3]);
        }
        __builtin_amdgcn_sched_barrier(0);

        // ---- step 3: consume loads (vmcnt wait lands HERE), mask, cvt,
        //      ds_write rows [W+19,W+34] (disjoint from read slots) ----
        if (t + 1 < TPB) {
            #pragma unroll
            for (int i = 0; i < 5; ++i) {
                const int gr = W + 19 + ro_[i];
                const unsigned m = ((unsigned)gr < (unsigned)HW) ? cm_[i] : 0u;
                U32H2 a, b;
                a.h = __builtin_amdgcn_cvt_pkrtz(
                          __uint_as_float(__float_as_uint(rf[i].x) & m),
                          __uint_as_float(__float_as_uint(rf[i].y) & m));
                b.h = __builtin_amdgcn_cvt_pkrtz(
                          __uint_as_float(__float_as_uint(rf[i].z) & m),
                          __uint_as_float(__float_as_uint(rf[i].w) & m));
                ((uint2*)ring)[sm_[i] * 20 + go_[i]] = make_uint2(a.u, b.u);
                sm_[i] += 16;
                sm_[i] -= (sm_[i] >= RING) ? RING : 0;
            }
        }

        // advance read-base slot (wave-uniform); NO barrier.
        b0 += 16;
        b0 -= (b0 >= RING) ? RING : 0;
        __builtin_amdgcn_sched_barrier(0);
    }
}

extern "C" void kernel_launch(void* const* d_in, const int* in_sizes, int n_in,
                              void* d_out, int out_size, void* d_ws, size_t ws_size,
                              hipStream_t stream) {
    const float* x = (const float*)d_in[0];
    const float* k = (const float*)d_in[1];
    float* out = (float*)d_out;

    dim3 grid(2 * 16 * 64, 1, 1);   // 2048 blocks: 2 per plane
    dim3 block(256);
    dwconv7_mish_wring<<<grid, block, 0, stream>>>(x, k, out);
}

// Round 24
// 119.317 us; speedup vs baseline: 1.0086x; 1.0086x over previous
//
#include <hip/hip_runtime.h>

// Depthwise 7x7 true-convolution (flipped kernel, SAME zero pad) + mish,
// via MFMA (v_mfma_f32_16x16x32_f16) with banded-Toeplitz weight matrices.
// Round-24 = round-22 trunk (114.7us) with FULL-PLANE blocks:
//   grid 1024 (1 block = 1 plane, 16 tiles) instead of 2048 half-planes.
//   -> exactly 4 blocks/CU, single generation (no second wave of blocks),
//   half the prologues (B-build + 2 full barriers + 22-row serial stage),
//   no generation boundary. Ring disjointness proof is split-independent.
//
//  - Block = one plane (256 rows) = 16 tiles of 16 rows x 256 cols.
//    Wave w owns the 64-col strip c0 = 64w.
//  - 40-slot ring of full-width f16 rows (PITCH 272: 8-half zero pad + 256
//    data + 8-half pad; pads written once -> SAME pad, no column checks).
//  - Reads [W-3,W+18] vs writes [W+19,W+34]: diff 1..37 mod 40, disjoint.
//    One drain-free barrier per tile. Each plane row staged exactly once.
//  - T14 split: step 1 issues tile t+1's RAW loads; step 2 computes tile t
//    (28 MFMA + mish + stores); step 3 consumes loads (vmcnt wait lands
//    there), cvt + ds_write; step 4 lgkmcnt(0)+s_barrier (no vmcnt drain).
//  - A-read banks: start bank 8*(lrow&3)+4*lk+const -> uniform 8 words/bank
//    = ds_read_b128 floor. B aliased into ring at init.
//  - waves_per_eu(2,7): allocator-free regime (R19/R20: min>=4 pins the
//    64-VGPR tier and spills anything bigger).
//
// Math per 16x16 output subtile, kernel row p:
//   C[i,j] += A_p[i,:] x B_p[:,j],  A_p[i,k] = Xf16[W+i+p-3, c0+16t4-8+k],
//   B_p[k,j] = W'[p][k-j-5] (banded), W'[p][q] = kern[6-p][6-q].
// MFMA C layout (m89): col = lane&15, row = (lane>>4)*4 + reg.

#define HW 256
#define RING 40
#define PITCH 272          // halfs per ring row (544 B)
#define TPB 16             // tiles per block (full plane)

typedef _Float16 f16x8 __attribute__((ext_vector_type(8)));
typedef float    f32x4 __attribute__((ext_vector_type(4)));
typedef __fp16   h2    __attribute__((ext_vector_type(2)));
union U32H2 { unsigned u; h2 h; };
union BFU   { uint4 u; f16x8 h; };

__device__ __forceinline__ float mish_f(float y) {
    float t = __expf(y);            // inf-safe: d -> inf -> 2/d -> 0 -> y*1
    float u = 1.0f + t;
    float d = __fmaf_rn(u, u, 1.0f);
    return y * (1.0f - __fdividef(2.0f, d));
}

__global__ __launch_bounds__(256)
__attribute__((amdgpu_waves_per_eu(2, 7)))
void dwconv7_mish_ring7(const float* __restrict__ x,
                        const float* __restrict__ kern,
                        float* __restrict__ out) {
    __shared__ __align__(16) _Float16 ring[RING * PITCH];   // 21,760 B
    unsigned* lds_B = (unsigned*)ring;                      // init-time alias

    const int tid  = threadIdx.x;
    const int lane = tid & 63;
    const int w    = tid >> 6;           // wave -> 64-col strip
    const int lrow = lane & 15;
    const int lk   = lane >> 4;
    const int c0   = w << 6;

    const int plane = blockIdx.x;        // 1024 planes, 1 block each

    const float* __restrict__ xp = x + (size_t)plane * (HW * HW);
    float* __restrict__ op = out + (size_t)plane * (HW * HW);

    // Flipped kernel in SGPRs: kf[p*7+q] = kern[6-p][6-q]
    float kf[49];
    #pragma unroll
    for (int i = 0; i < 49; ++i) {
        int p = i / 7, q = i - p * 7;
        kf[i] = __int_as_float(__builtin_amdgcn_readfirstlane(
                    __float_as_int(kern[(6 - p) * 7 + (6 - q)])));
    }

    // Banded-Toeplitz B_p[16][32] f16, word idx = p*256 + j*16 + k/2.
    {
        const int j  = tid >> 4;
        const int kw = tid & 15;
        #pragma unroll
        for (int p = 0; p < 7; ++p) {
            const int d0 = 2 * kw - j - 5;
            const int d1 = d0 + 1;
            float v0 = 0.f, v1 = 0.f;
            #pragma unroll
            for (int q = 0; q < 7; ++q) {
                v0 = (d0 == q) ? kf[p * 7 + q] : v0;
                v1 = (d1 == q) ? kf[p * 7 + q] : v1;
            }
            U32H2 u; u.h = __builtin_amdgcn_cvt_pkrtz(v0, v1);
            lds_B[p * 256 + tid] = u.u;
        }
    }
    __syncthreads();

    // B fragments hoisted: B[k=8lk+e, j=lrow], contiguous 16 B per lane.
    f16x8 bfrag[7];
    #pragma unroll
    for (int p = 0; p < 7; ++p) {
        BFU bu;
        bu.u = ((const uint4*)lds_B)[(p << 6) + (lrow << 2) + lk];
        bfrag[p] = bu.h;
    }
    __syncthreads();   // bfrag reads done before ring overwrites the B alias

    // Zero the horizontal pads once: 40 rows x {halfs 0..7, 264..271}.
    if (tid < 160) {
        int row = tid >> 2, q = tid & 3;
        ((uint2*)ring)[row * 68 + (q < 2 ? q : 64 + q)] = make_uint2(0u, 0u);
    }

    // Prologue: stage rows gr = -3 .. 18 (22 rows; OOB rows -> zeros).
    #pragma unroll
    for (int i = 0; i < 6; ++i) {
        const int row = w + 4 * i;            // wave-uniform
        if (row < 22) {
            const int gr = row - 3;
            const int slot = (gr + RING) % RING;
            float4 f = make_float4(0.f, 0.f, 0.f, 0.f);
            if ((unsigned)gr < (unsigned)HW)
                f = *(const float4*)(xp + (gr << 8) + 4 * lane);
            U32H2 a, b;
            a.h = __builtin_amdgcn_cvt_pkrtz(f.x, f.y);
            b.h = __builtin_amdgcn_cvt_pkrtz(f.z, f.w);
            ((uint2*)ring)[slot * 68 + 2 + lane] = make_uint2(a.u, b.u);
        }
    }
    __syncthreads();

    float4 rf[4];

    #pragma unroll 1
    for (int t = 0; t < TPB; ++t) {
        const int W = t << 4;                 // tile's first output row

        // ---- step 1: issue next tile's RAW loads (rows W+19..W+34) ----
        if (t + 1 < TPB) {
            #pragma unroll
            for (int i = 0; i < 4; ++i) {
                const int gr = W + 19 + w + 4 * i;       // wave-uniform
                rf[i] = make_float4(0.f, 0.f, 0.f, 0.f);
                if (gr < HW)
                    rf[i] = *(const float4*)(xp + (gr << 8) + 4 * lane);
            }
        }
        __builtin_amdgcn_sched_barrier(0);

        // ---- step 2: compute tile (16 rows x 64 cols per wave) ----
        const int b0 = (W + 37) % RING;       // slot of gr = W-3
        int sa[7];                            // per-lane row base (halfs)
        #pragma unroll
        for (int p = 0; p < 7; ++p) {
            int s = b0 + lrow + p;
            s -= (s >= RING) ? RING : 0;
            sa[p] = s * PITCH;
        }
        #pragma unroll
        for (int t4 = 0; t4 < 4; ++t4) {
            f32x4 acc = {0.f, 0.f, 0.f, 0.f};
            #pragma unroll
            for (int p = 0; p < 7; ++p) {
                f16x8 a = *(const f16x8*)(ring + sa[p] + c0 + 16 * t4 + 8 * lk);
                acc = __builtin_amdgcn_mfma_f32_16x16x32_f16(a, bfrag[p], acc,
                                                             0, 0, 0);
            }
            const int col = c0 + 16 * t4 + lrow;
            const int rb  = W + (lk << 2);
            op[(rb + 0) * HW + col] = mish_f(acc[0]);
            op[(rb + 1) * HW + col] = mish_f(acc[1]);
            op[(rb + 2) * HW + col] = mish_f(acc[2]);
            op[(rb + 3) * HW + col] = mish_f(acc[3]);
        }
        __builtin_amdgcn_sched_barrier(0);

        // ---- step 3: consume loads (vmcnt wait lands HERE), cvt, ds_write
        //      (write slots disjoint from this tile's read slots mod 40) ----
        if (t + 1 < TPB) {
            #pragma unroll
            for (int i = 0; i < 4; ++i) {
                const int gr = W + 19 + w + 4 * i;
                const int slot = gr % RING;
                U32H2 a, b;
                a.h = __builtin_amdgcn_cvt_pkrtz(rf[i].x, rf[i].y);
                b.h = __builtin_amdgcn_cvt_pkrtz(rf[i].z, rf[i].w);
                ((uint2*)ring)[slot * 68 + 2 + lane] = make_uint2(a.u, b.u);
            }
        }

        // ---- step 4: drain-free barrier (LDS visibility only) ----
        asm volatile("s_waitcnt lgkmcnt(0)\n\ts_barrier" ::: "memory");
        __builtin_amdgcn_sched_barrier(0);
    }
}

extern "C" void kernel_launch(void* const* d_in, const int* in_sizes, int n_in,
                              void* d_out, int out_size, void* d_ws, size_t ws_size,
                              hipStream_t stream) {
    const float* x = (const float*)d_in[0];
    const float* k = (const float*)d_in[1];
    float* out = (float*)d_out;

    dim3 grid(16 * 64, 1, 1);   // 1024 blocks: 1 per plane, 4/CU resident
    dim3 block(256);
    dwconv7_mish_ring7<<<grid, block, 0, stream>>>(x, k, out);
}

// Round 26
// 117.430 us; speedup vs baseline: 1.0248x; 1.0161x over previous
//
#include <hip/hip_runtime.h>

// Depthwise 7x7 true-convolution (flipped kernel, SAME zero pad) + mish,
// via MFMA (v_mfma_f32_16x16x32_f16) with banded-Toeplitz weight matrices.
// Round-26 = round-25 (32-row phases) with the prologue slot-mod bug fixed:
// conditional-subtract only handled ONE wrap; r0=128 blocks have gr up to
// 162 -> needs true % RING. (R25 failed with absmax 64.5 from reading
// never-written ring slots in the upper half-plane blocks.)
//
// 32-ROW PHASES (2 sub-tiles per barrier): halves every per-phase fixed
// cost (vmcnt wait, lgkmcnt drain, s_barrier, sa recompute, ramp) and makes
// the compute phase (~56 MFMA + 2x mish ~1200cyc) exceed HBM latency
// (~900cyc) so step-3's vmcnt wait ~vanishes without depth-2 state.
//  - Block = half plane = 4 phases x 32 rows x 256 cols. Wave w owns the
//    64-col strip c0=64w; per phase computes 2 sub-tiles of 16 rows.
//  - 70-slot ring (PITCH 272: 8-half zero pad + 256 data + 8-half pad).
//    Reads [W-3,W+34] vs writes [W+35,W+66]: diffs 1..69, nonzero mod 70
//    -> disjoint. One drain-free barrier per phase.
//  - T14 split: 8 RAW loads at phase start, consume+cvt+ds_write after
//    compute. A-read banks: uniform 8 words/bank = ds_read_b128 floor.
//  - waves_per_eu(2,4): allocator-free regime (R19/R20: min>=4 pins the
//    64-VGPR tier and spills; structure needs ~110).
//
// Math per 16x16 output subtile, kernel row p:
//   C[i,j] += A_p[i,:] x B_p[:,j],  A_p[i,k] = Xf16[W+i+p-3, c0+16t4-8+k],
//   B_p[k,j] = W'[p][k-j-5] (banded), W'[p][q] = kern[6-p][6-q].
// MFMA C layout (m89): col = lane&15, row = (lane>>4)*4 + reg.

#define HW 256
#define RING 70
#define PITCH 272          // halfs per ring row (544 B)
#define NPH 4              // phases per block (32 rows each)

typedef _Float16 f16x8 __attribute__((ext_vector_type(8)));
typedef float    f32x4 __attribute__((ext_vector_type(4)));
typedef __fp16   h2    __attribute__((ext_vector_type(2)));
union U32H2 { unsigned u; h2 h; };
union BFU   { uint4 u; f16x8 h; };

__device__ __forceinline__ float mish_f(float y) {
    float t = __expf(y);            // inf-safe: d -> inf -> 2/d -> 0 -> y*1
    float u = 1.0f + t;
    float d = __fmaf_rn(u, u, 1.0f);
    return y * (1.0f - __fdividef(2.0f, d));
}

__global__ __launch_bounds__(256)
__attribute__((amdgpu_waves_per_eu(2, 4)))
void dwconv7_mish_ring9(const float* __restrict__ x,
                        const float* __restrict__ kern,
                        float* __restrict__ out) {
    __shared__ __align__(16) _Float16 ring[RING * PITCH];   // 38,080 B
    unsigned* lds_B = (unsigned*)ring;                      // init-time alias

    const int tid  = threadIdx.x;
    const int lane = tid & 63;
    const int w    = tid >> 6;           // wave -> 64-col strip
    const int lrow = lane & 15;
    const int lk   = lane >> 4;
    const int c0   = w << 6;

    const int bid   = blockIdx.x;
    const int plane = bid >> 1;
    const int r0    = (bid & 1) << 7;    // 0 or 128

    const float* __restrict__ xp = x + (size_t)plane * (HW * HW);
    float* __restrict__ op = out + (size_t)plane * (HW * HW);

    // Flipped kernel in SGPRs: kf[p*7+q] = kern[6-p][6-q]
    float kf[49];
    #pragma unroll
    for (int i = 0; i < 49; ++i) {
        int p = i / 7, q = i - p * 7;
        kf[i] = __int_as_float(__builtin_amdgcn_readfirstlane(
                    __float_as_int(kern[(6 - p) * 7 + (6 - q)])));
    }

    // Banded-Toeplitz B_p[16][32] f16, word idx = p*256 + j*16 + k/2.
    {
        const int j  = tid >> 4;
        const int kw = tid & 15;
        #pragma unroll
        for (int p = 0; p < 7; ++p) {
            const int d0 = 2 * kw - j - 5;
            const int d1 = d0 + 1;
            float v0 = 0.f, v1 = 0.f;
            #pragma unroll
            for (int q = 0; q < 7; ++q) {
                v0 = (d0 == q) ? kf[p * 7 + q] : v0;
                v1 = (d1 == q) ? kf[p * 7 + q] : v1;
            }
            U32H2 u; u.h = __builtin_amdgcn_cvt_pkrtz(v0, v1);
            lds_B[p * 256 + tid] = u.u;
        }
    }
    __syncthreads();

    // B fragments hoisted: B[k=8lk+e, j=lrow], contiguous 16 B per lane.
    f16x8 bfrag[7];
    #pragma unroll
    for (int p = 0; p < 7; ++p) {
        BFU bu;
        bu.u = ((const uint4*)lds_B)[(p << 6) + (lrow << 2) + lk];
        bfrag[p] = bu.h;
    }
    __syncthreads();   // bfrag reads done before ring overwrites the B alias

    // Zero the horizontal pads once: 70 rows x {uint2 slots 0,1,66,67}.
    #pragma unroll
    for (int i = 0; i < 2; ++i) {
        int s = tid + (i << 8);
        if (s < 280) {
            int row = s >> 2, q = s & 3;
            ((uint2*)ring)[row * 68 + (q < 2 ? q : 64 + q)] = make_uint2(0u, 0u);
        }
    }

    // Prologue: stage rows gr = r0-3 .. r0+34 (38 rows; OOB -> zeros).
    // TRUE modulo: gr ranges [-3, 162] across the two half-plane cases.
    #pragma unroll
    for (int i = 0; i < 10; ++i) {
        const int row = w + 4 * i;            // wave-uniform
        if (row < 38) {
            const int gr = r0 - 3 + row;
            const int slot = (gr + RING) % RING;
            float4 f = make_float4(0.f, 0.f, 0.f, 0.f);
            if ((unsigned)gr < (unsigned)HW)
                f = *(const float4*)(xp + (gr << 8) + 4 * lane);
            U32H2 a, b;
            a.h = __builtin_amdgcn_cvt_pkrtz(f.x, f.y);
            b.h = __builtin_amdgcn_cvt_pkrtz(f.z, f.w);
            ((uint2*)ring)[slot * 68 + 2 + lane] = make_uint2(a.u, b.u);
        }
    }
    __syncthreads();

    // Per-thread write-slot bases (rows W+35+w+4i at phase t), advanced
    // +32 mod 70 per phase (bounded: sm_<70, +32<102 -> one subtract OK).
    int sm_[8];
    #pragma unroll
    for (int i = 0; i < 8; ++i) sm_[i] = (r0 + 35 + w + 4 * i) % RING;

    float4 rf[8];

    #pragma unroll 1
    for (int t = 0; t < NPH; ++t) {
        const int W = r0 + (t << 5);          // phase's first output row

        // ---- step 1: issue next phase's RAW loads (rows W+35..W+66) ----
        if (t + 1 < NPH) {
            #pragma unroll
            for (int i = 0; i < 8; ++i) {
                const int gr = W + 35 + w + 4 * i;       // wave-uniform
                rf[i] = make_float4(0.f, 0.f, 0.f, 0.f);
                if (gr < HW)
                    rf[i] = *(const float4*)(xp + (gr << 8) + 4 * lane);
            }
        }
        __builtin_amdgcn_sched_barrier(0);

        // ---- step 2: compute 2 sub-tiles (32 rows x 64 cols per wave) ----
        const int b0 = (W + 67) % RING;       // slot of gr = W-3 (true mod)
        #pragma unroll
        for (int st = 0; st < 2; ++st) {
            int sa[7];                        // b0+31+6 max = 106 -> one sub
            #pragma unroll
            for (int p = 0; p < 7; ++p) {
                int s = b0 + (st << 4) + lrow + p;
                s -= (s >= RING) ? RING : 0;
                sa[p] = s * PITCH;
            }
            #pragma unroll
            for (int t4 = 0; t4 < 4; ++t4) {
                f32x4 acc = {0.f, 0.f, 0.f, 0.f};
                #pragma unroll
                for (int p = 0; p < 7; ++p) {
                    f16x8 a = *(const f16x8*)(ring + sa[p] + c0 + 16 * t4 + 8 * lk);
                    acc = __builtin_amdgcn_mfma_f32_16x16x32_f16(a, bfrag[p], acc,
                                                                 0, 0, 0);
                }
                const int col = c0 + 16 * t4 + lrow;
                const int rb  = W + (st << 4) + (lk << 2);
                op[(rb + 0) * HW + col] = mish_f(acc[0]);
                op[(rb + 1) * HW + col] = mish_f(acc[1]);
                op[(rb + 2) * HW + col] = mish_f(acc[2]);
                op[(rb + 3) * HW + col] = mish_f(acc[3]);
            }
        }
        __builtin_amdgcn_sched_barrier(0);

        // ---- step 3: consume loads (vmcnt wait lands HERE; loads had a
        //      full 56-MFMA phase to land), cvt, ds_write ----
        if (t + 1 < NPH) {
            #pragma unroll
            for (int i = 0; i < 8; ++i) {
                U32H2 a, b;
                a.h = __builtin_amdgcn_cvt_pkrtz(rf[i].x, rf[i].y);
                b.h = __builtin_amdgcn_cvt_pkrtz(rf[i].z, rf[i].w);
                ((uint2*)ring)[sm_[i] * 68 + 2 + lane] = make_uint2(a.u, b.u);
                sm_[i] += 32;
                sm_[i] -= (sm_[i] >= RING) ? RING : 0;
            }
        }

        // ---- step 4: drain-free barrier (LDS visibility only) ----
        asm volatile("s_waitcnt lgkmcnt(0)\n\ts_barrier" ::: "memory");
        __builtin_amdgcn_sched_barrier(0);
    }
}

extern "C" void kernel_launch(void* const* d_in, const int* in_sizes, int n_in,
                              void* d_out, int out_size, void* d_ws, size_t ws_size,
                              hipStream_t stream) {
    const float* x = (const float*)d_in[0];
    const float* k = (const float*)d_in[1];
    float* out = (float*)d_out;

    dim3 grid(2 * 16 * 64, 1, 1);   // 2048 blocks: 2 per plane
    dim3 block(256);
    dwconv7_mish_ring9<<<grid, block, 0, stream>>>(x, k, out);
}